// Round 1
// baseline (1940.067 us; speedup 1.0000x reference)
//
#include <hip/hip_runtime.h>
#include <stdint.h>

// ---------------- problem constants ----------------
constexpr int BZ   = 64;          // batch
constexpr int SEQ  = 577;         // sequence length
constexpr int DM   = 768;         // model dim
constexpr int NH   = 12;          // heads
constexpr int HD   = 64;          // head dim
constexpr int FFD  = 3072;        // mlp hidden
constexpr int ROWS = BZ * SEQ;    // 36928 token rows
constexpr int BHN  = BZ * NH;     // 768 (b,h) pairs
constexpr int VTS  = 608;         // padded t-stride for V^T (19*32 >= 592 >= 577)

typedef __attribute__((ext_vector_type(8))) short bf16x8;  // 8 bf16 = 4 VGPRs
typedef __attribute__((ext_vector_type(4))) float f32x4;   // MFMA C/D frag

static __device__ __forceinline__ unsigned short f2bf(float f) {
  union { float f; uint32_t u; } v; v.f = f;
  uint32_t r = (v.u + 0x7FFFu + ((v.u >> 16) & 1u)) >> 16;  // RNE
  return (unsigned short)r;
}

static __device__ __forceinline__ f32x4 mfma16(bf16x8 a, bf16x8 b, f32x4 c) {
  return __builtin_amdgcn_mfma_f32_16x16x32_bf16(a, b, c, 0, 0, 0);
}

// ---------------- weight prep: fp32 -> bf16, transposed to [N][K] ----------------
// Wq/Wk/Wv are [H, D, HD]; stacked QKV weight-transpose: dst[n*768 + k],
// n in [0,2304): seg 0=Q,1=K,2=V; within-seg col = h*64+e.
__global__ __launch_bounds__(256) void prep_qkv(const float* __restrict__ Wq,
                                                const float* __restrict__ Wk,
                                                const float* __restrict__ Wv,
                                                unsigned short* __restrict__ dst) {
  int tid = blockIdx.x * 256 + threadIdx.x;           // 2304*768 total, exact grid
  int n = tid / DM, k = tid - n * DM;
  int seg = n / DM;                                    // 0..2
  int within = n - seg * DM;
  int h = within >> 6, e = within & 63;
  const float* W = (seg == 0) ? Wq : (seg == 1) ? Wk : Wv;
  dst[tid] = f2bf(W[((size_t)h * DM + k) * HD + e]);
}

// generic [K,N] fp32 -> [N,K] bf16 transpose-cast
__global__ __launch_bounds__(256) void prep_t(const float* __restrict__ src,
                                              unsigned short* __restrict__ dst,
                                              int N, int K) {
  int tid = blockIdx.x * 256 + threadIdx.x;
  if (tid >= N * K) return;
  int n = tid / K, k = tid - n * K;
  dst[tid] = f2bf(src[(size_t)k * N + n]);
}

// ---------------- layernorm: fp32 [rows,768] -> bf16 [rows,768] ----------------
__global__ __launch_bounds__(256) void ln_bf16(const float* __restrict__ X,
                                               const float* __restrict__ g,
                                               const float* __restrict__ b,
                                               unsigned short* __restrict__ out) {
  int row  = blockIdx.x * 4 + (threadIdx.x >> 6);   // 4 waves/block, wave per row
  int lane = threadIdx.x & 63;
  const float* x = X + (size_t)row * DM;
  float4 v[3];
  float s = 0.f, s2 = 0.f;
#pragma unroll
  for (int i = 0; i < 3; i++) {
    v[i] = *(const float4*)(x + i * 256 + lane * 4);
    s  += v[i].x + v[i].y + v[i].z + v[i].w;
    s2 += v[i].x * v[i].x + v[i].y * v[i].y + v[i].z * v[i].z + v[i].w * v[i].w;
  }
#pragma unroll
  for (int o = 1; o < 64; o <<= 1) { s += __shfl_xor(s, o); s2 += __shfl_xor(s2, o); }
  float mu  = s * (1.f / DM);
  float var = s2 * (1.f / DM) - mu * mu;
  float inv = rsqrtf(var + 1e-6f);
#pragma unroll
  for (int i = 0; i < 3; i++) {
    int c = i * 256 + lane * 4;
    float4 gg = *(const float4*)(g + c);
    float4 bb = *(const float4*)(b + c);
    ushort4 o4;
    o4.x = f2bf((v[i].x - mu) * inv * gg.x + bb.x);
    o4.y = f2bf((v[i].y - mu) * inv * gg.y + bb.y);
    o4.z = f2bf((v[i].z - mu) * inv * gg.z + bb.z);
    o4.w = f2bf((v[i].w - mu) * inv * gg.w + bb.w);
    *(ushort4*)(out + (size_t)row * DM + c) = o4;
  }
}

// ---------------- tiled bf16 MFMA GEMM: C = A[M,K] * Bt[N,K]^T ----------------
// 128x128 tile, BK=32, 256 threads (2x2 waves, each wave 64x64 = 4x4 MFMA tiles).
// Fragment layouts (guide-verified): A[m=lane&15][k=quad*8+j], B[k=quad*8+j][n=lane&15],
// C/D col=lane&15, row=quad*4+reg.
// EPI: 0=QKV scatter, 1=Wo + x residual -> fp32 out, 2=W1+GELU -> bf16, 3=W2 += into fp32 out
template <int EPI>
__global__ __launch_bounds__(256) void gemm_bt(
    const unsigned short* __restrict__ A, const unsigned short* __restrict__ Bt,
    int M, int N, int K,
    const float* __restrict__ bias0, const float* __restrict__ bias1,
    const float* __restrict__ bias2, const float* __restrict__ xres,
    float* __restrict__ outf,
    unsigned short* __restrict__ ob0, unsigned short* __restrict__ ob1,
    unsigned short* __restrict__ ob2) {
  __shared__ __align__(16) unsigned short sA[128 * 32];
  __shared__ __align__(16) unsigned short sB[128 * 32];
  const int tid  = threadIdx.x;
  const int wave = tid >> 6, lane = tid & 63;
  const int l15 = lane & 15, quad = lane >> 4;
  const int m0 = blockIdx.y * 128, n0 = blockIdx.x * 128;
  const int wm = (wave >> 1) * 64, wn = (wave & 1) * 64;

  f32x4 acc[4][4] = {};
  const int nkt = K >> 5;
  for (int kt = 0; kt < nkt; ++kt) {
    // stage 8KB A-tile + 8KB B-tile; 16B per lane-op, layout == global k-contiguous rows
#pragma unroll
    for (int i = 0; i < 2; i++) {
      int c = tid + i * 256;
      int row = c >> 2, kc = (c & 3) << 3;
      int ra = m0 + row; if (ra >= M) ra = M - 1;           // clamp tail rows
      bf16x8 va = *(const bf16x8*)(A  + (size_t)ra * K        + (kt << 5) + kc);
      bf16x8 vb = *(const bf16x8*)(Bt + (size_t)(n0 + row) * K + (kt << 5) + kc);
      *(bf16x8*)(sA + row * 32 + kc) = va;
      *(bf16x8*)(sB + row * 32 + kc) = vb;
    }
    __syncthreads();
    bf16x8 aF[4], bF[4];
#pragma unroll
    for (int mi = 0; mi < 4; mi++) aF[mi] = *(const bf16x8*)(sA + (wm + mi * 16 + l15) * 32 + quad * 8);
#pragma unroll
    for (int ni = 0; ni < 4; ni++) bF[ni] = *(const bf16x8*)(sB + (wn + ni * 16 + l15) * 32 + quad * 8);
#pragma unroll
    for (int mi = 0; mi < 4; mi++)
#pragma unroll
      for (int ni = 0; ni < 4; ni++) acc[mi][ni] = mfma16(aF[mi], bF[ni], acc[mi][ni]);
    __syncthreads();
  }

  // ---- epilogue ----
#pragma unroll
  for (int mi = 0; mi < 4; mi++) {
#pragma unroll
    for (int r = 0; r < 4; r++) {
      int mg = m0 + wm + mi * 16 + quad * 4 + r;   // global row (token index)
      if (mg >= M) continue;
      if constexpr (EPI == 0) {
        int bb = mg / SEQ, ss = mg - bb * SEQ;
        int seg = n0 / DM;                          // uniform per block (768%128==0)
        int within0 = n0 - seg * DM + wn;
#pragma unroll
        for (int ni = 0; ni < 4; ni++) {
          int wcol = within0 + ni * 16 + l15;       // 0..767 = h*64+e
          int h = wcol >> 6, e = wcol & 63;
          float val = acc[mi][ni][r];
          if (seg == 0) {
            float qv = (val + bias0[wcol]) * 0.125f;   // fold 1/sqrt(64)
            ob0[((size_t)(bb * NH + h) * SEQ + ss) * HD + e] = f2bf(qv);
          } else if (seg == 1) {
            float kv = val + bias1[wcol];
            ob1[((size_t)(bb * NH + h) * SEQ + ss) * HD + e] = f2bf(kv);
          } else {
            float vv = val + bias2[wcol];
            ob2[((size_t)(bb * NH + h) * HD + e) * VTS + ss] = f2bf(vv);  // V transposed
          }
        }
      } else if constexpr (EPI == 1) {
        size_t base = (size_t)mg * DM;
#pragma unroll
        for (int ni = 0; ni < 4; ni++) {
          int col = n0 + wn + ni * 16 + l15;
          outf[base + col] = xres[base + col] + acc[mi][ni][r] + bias0[col];
        }
      } else if constexpr (EPI == 2) {
        size_t base = (size_t)mg * FFD;
#pragma unroll
        for (int ni = 0; ni < 4; ni++) {
          int col = n0 + wn + ni * 16 + l15;
          float xv = acc[mi][ni][r] + bias0[col];
          float u  = 0.7978845608028654f * (xv + 0.044715f * xv * xv * xv);
          float uc = fminf(fmaxf(u, -15.f), 15.f);
          float t  = __expf(2.f * uc);
          float gel = 0.5f * xv * (1.f + (t - 1.f) / (t + 1.f));
          ob0[base + col] = f2bf(gel);
        }
      } else {  // EPI == 3
        size_t base = (size_t)mg * DM;
#pragma unroll
        for (int ni = 0; ni < 4; ni++) {
          int col = n0 + wn + ni * 16 + l15;
          outf[base + col] += acc[mi][ni][r] + bias0[col];
        }
      }
    }
  }
}

// ---------------- attention: one wave per (bh, 16-row q-tile) ----------------
// Two-phase softmax: pass A = QK^T row maxes (in-register + shuffle reduce);
// pass B = recompute QK^T, p=exp(s-max) -> 1.3KB LDS transpose -> PV MFMA.
// 1/sum folded into epilogue. Q pre-scaled by 0.125 at QKV epilogue.
__global__ __launch_bounds__(64) void attn_kernel(
    const unsigned short* __restrict__ Q, const unsigned short* __restrict__ Kb,
    const unsigned short* __restrict__ Vt, unsigned short* __restrict__ Cc) {
  __shared__ __align__(16) unsigned short sP[16 * 40];   // [16 q-rows][32 t] stride 40
  int lane = threadIdx.x;
  int quad = lane >> 4, l15 = lane & 15;
  int qb = blockIdx.x, bh = blockIdx.y;
  int q0 = qb * 16;

  int srow = q0 + l15; if (srow > SEQ - 1) srow = SEQ - 1;   // clamp tail q rows
  const unsigned short* qrow = Q + ((size_t)bh * SEQ + srow) * HD;
  bf16x8 aQ0 = *(const bf16x8*)(qrow + quad * 8);
  bf16x8 aQ1 = *(const bf16x8*)(qrow + 32 + quad * 8);

  // pass A: row maxes
  float mx[4] = {-1e30f, -1e30f, -1e30f, -1e30f};
  for (int tt = 0; tt < 37; ++tt) {
    int t = tt * 16 + l15;
    int tr = (t > SEQ - 1) ? SEQ - 1 : t;
    const unsigned short* krow = Kb + ((size_t)bh * SEQ + tr) * HD;
    bf16x8 b0 = *(const bf16x8*)(krow + quad * 8);
    bf16x8 b1 = *(const bf16x8*)(krow + 32 + quad * 8);
    f32x4 acc = {0.f, 0.f, 0.f, 0.f};
    acc = mfma16(aQ0, b0, acc);
    acc = mfma16(aQ1, b1, acc);
#pragma unroll
    for (int r = 0; r < 4; r++) mx[r] = (t < SEQ) ? fmaxf(mx[r], acc[r]) : mx[r];
  }
#pragma unroll
  for (int o = 1; o < 16; o <<= 1)
#pragma unroll
    for (int r = 0; r < 4; r++) mx[r] = fmaxf(mx[r], __shfl_xor(mx[r], o));

  // pass B: exp + PV
  f32x4 accO[4] = {};
  float lsum[4] = {0.f, 0.f, 0.f, 0.f};
  for (int kt = 0; kt < 19; ++kt) {
#pragma unroll
    for (int hh = 0; hh < 2; ++hh) {
      int tt = kt * 2 + hh;
      float p[4] = {0.f, 0.f, 0.f, 0.f};
      if (tt < 37) {
        int t = tt * 16 + l15;
        int tr = (t > SEQ - 1) ? SEQ - 1 : t;
        const unsigned short* krow = Kb + ((size_t)bh * SEQ + tr) * HD;
        bf16x8 b0 = *(const bf16x8*)(krow + quad * 8);
        bf16x8 b1 = *(const bf16x8*)(krow + 32 + quad * 8);
        f32x4 acc = {0.f, 0.f, 0.f, 0.f};
        acc = mfma16(aQ0, b0, acc);
        acc = mfma16(aQ1, b1, acc);
        if (t < SEQ) {
#pragma unroll
          for (int r = 0; r < 4; r++) { p[r] = __expf(acc[r] - mx[r]); lsum[r] += p[r]; }
        }
      }
#pragma unroll
      for (int r = 0; r < 4; r++) sP[(quad * 4 + r) * 40 + hh * 16 + l15] = f2bf(p[r]);
    }
    // C-layout -> A-layout transpose via LDS (single wave: DS ops are wave-ordered)
    bf16x8 aP = *(const bf16x8*)(sP + l15 * 40 + quad * 8);
#pragma unroll
    for (int ni = 0; ni < 4; ni++) {
      bf16x8 bV = *(const bf16x8*)(Vt + ((size_t)bh * HD + ni * 16 + l15) * VTS + kt * 32 + quad * 8);
      accO[ni] = mfma16(aP, bV, accO[ni]);
    }
  }
#pragma unroll
  for (int o = 1; o < 16; o <<= 1)
#pragma unroll
    for (int r = 0; r < 4; r++) lsum[r] += __shfl_xor(lsum[r], o);

  int bb = bh / NH, h = bh - bb * NH;
#pragma unroll
  for (int r = 0; r < 4; r++) {
    int ss = q0 + quad * 4 + r;
    if (ss < SEQ) {
      float inv = 1.f / lsum[r];
      size_t base = ((size_t)bb * SEQ + ss) * DM + h * HD;
#pragma unroll
      for (int ni = 0; ni < 4; ni++)
        Cc[base + ni * 16 + l15] = f2bf(accO[ni][r] * inv);
    }
  }
}

// ---------------- host ----------------
extern "C" void kernel_launch(void* const* d_in, const int* in_sizes, int n_in,
                              void* d_out, int out_size, void* d_ws, size_t ws_size,
                              hipStream_t stream) {
  (void)in_sizes; (void)n_in; (void)out_size; (void)ws_size;
  const float* x     = (const float*)d_in[0];
  const float* ln1_g = (const float*)d_in[1];
  const float* ln1_b = (const float*)d_in[2];
  const float* Wq    = (const float*)d_in[3];
  const float* bq    = (const float*)d_in[4];
  const float* Wk    = (const float*)d_in[5];
  const float* bk    = (const float*)d_in[6];
  const float* Wv    = (const float*)d_in[7];
  const float* bv    = (const float*)d_in[8];
  const float* Wo    = (const float*)d_in[9];
  const float* bo    = (const float*)d_in[10];
  const float* ln2_g = (const float*)d_in[11];
  const float* ln2_b = (const float*)d_in[12];
  const float* W1    = (const float*)d_in[13];
  const float* b1    = (const float*)d_in[14];
  const float* W2    = (const float*)d_in[15];
  const float* b2    = (const float*)d_in[16];
  float* out = (float*)d_out;

  char* ws = (char*)d_ws;
  size_t off = 0;
  auto alloc = [&](size_t bytes) -> unsigned short* {
    unsigned short* p = (unsigned short*)(ws + off);
    off += (bytes + 255) & ~(size_t)255;
    return p;
  };
  unsigned short* h_bf  = alloc((size_t)ROWS * DM * 2);          // also m_bf (LN2 out)
  unsigned short* q_bf  = alloc((size_t)BHN * SEQ * HD * 2);
  unsigned short* k_bf  = alloc((size_t)BHN * SEQ * HD * 2);
  unsigned short* vt_bf = alloc((size_t)BHN * HD * VTS * 2);
  unsigned short* cc_bf = alloc((size_t)ROWS * DM * 2);
  // g_bf (226.9MB) aliases [q_bf .. cc_bf end) (229.9MB) — q/k/vt/cc dead by then
  unsigned short* g_bf = q_bf;
  unsigned short* wqkv_t = alloc((size_t)2304 * 768 * 2);
  unsigned short* w1_t   = alloc((size_t)3072 * 768 * 2);
  unsigned short* w2_t   = alloc((size_t)768 * 3072 * 2);
  unsigned short* wo_t   = alloc((size_t)768 * 768 * 2);

  // weight prep (bf16 + transpose to [N][K])
  prep_qkv<<<(2304 * 768) / 256, 256, 0, stream>>>(Wq, Wk, Wv, wqkv_t);
  prep_t<<<(3072 * 768) / 256, 256, 0, stream>>>(W1, w1_t, 3072, 768);
  prep_t<<<(768 * 3072) / 256, 256, 0, stream>>>(W2, w2_t, 768, 3072);
  prep_t<<<(768 * 768) / 256, 256, 0, stream>>>(Wo, wo_t, 768, 768);

  // LN1
  ln_bf16<<<ROWS / 4, 256, 0, stream>>>(x, ln1_g, ln1_b, h_bf);
  // QKV projection (Q scaled by 1/8; V written transposed)
  gemm_bt<0><<<dim3(2304 / 128, (ROWS + 127) / 128), 256, 0, stream>>>(
      h_bf, wqkv_t, ROWS, 2304, 768, bq, bk, bv, nullptr, nullptr, q_bf, k_bf, vt_bf);
  // attention
  attn_kernel<<<dim3(37, BHN), 64, 0, stream>>>(q_bf, k_bf, vt_bf, cc_bf);
  // output projection + residual -> d_out (fp32)
  gemm_bt<1><<<dim3(768 / 128, (ROWS + 127) / 128), 256, 0, stream>>>(
      cc_bf, wo_t, ROWS, 768, 768, bo, nullptr, nullptr, x, out, nullptr, nullptr, nullptr);
  // LN2 (reads d_out)
  ln_bf16<<<ROWS / 4, 256, 0, stream>>>(out, ln2_g, ln2_b, h_bf);
  // MLP up + GELU
  gemm_bt<2><<<dim3(3072 / 128, (ROWS + 127) / 128), 256, 0, stream>>>(
      h_bf, w1_t, ROWS, 3072, 768, b1, nullptr, nullptr, nullptr, nullptr, g_bf, nullptr, nullptr);
  // MLP down + residual accumulate into d_out
  gemm_bt<3><<<dim3(768 / 128, (ROWS + 127) / 128), 256, 0, stream>>>(
      g_bf, w2_t, ROWS, 768, 3072, b2, nullptr, nullptr, nullptr, out, nullptr, nullptr, nullptr);
}

// Round 3
// 1598.739 us; speedup vs baseline: 1.2135x; 1.2135x over previous
//
#include <hip/hip_runtime.h>
#include <stdint.h>

// ---------------- problem constants ----------------
constexpr int BZ   = 64;          // batch
constexpr int SEQ  = 577;         // sequence length
constexpr int DM   = 768;         // model dim
constexpr int NH   = 12;          // heads
constexpr int HD   = 64;          // head dim
constexpr int FFD  = 3072;        // mlp hidden
constexpr int ROWS = BZ * SEQ;    // 36928 token rows
constexpr int BHN  = BZ * NH;     // 768 (b,h) pairs
constexpr int VTS  = 640;         // padded t-stride for V^T (10*64, allows full-tile 16B reads)

typedef __attribute__((ext_vector_type(8))) short bf16x8;  // 8 bf16 = 4 VGPRs
typedef __attribute__((ext_vector_type(4))) float f32x4;   // MFMA C/D frag

static __device__ __forceinline__ unsigned short f2bf(float f) {
  union { float f; uint32_t u; } v; v.f = f;
  uint32_t r = (v.u + 0x7FFFu + ((v.u >> 16) & 1u)) >> 16;  // RNE
  return (unsigned short)r;
}

static __device__ __forceinline__ f32x4 mfma16(bf16x8 a, bf16x8 b, f32x4 c) {
  return __builtin_amdgcn_mfma_f32_16x16x32_bf16(a, b, c, 0, 0, 0);
}

// async global->LDS, 16B per lane. LDS dest must be wave-uniform base + lane*16,
// which our staging layout satisfies (addr == linear_id * 16B).
static __device__ __forceinline__ void gload_lds16(const unsigned short* g, unsigned short* l) {
  __builtin_amdgcn_global_load_lds((const __attribute__((address_space(1))) unsigned int*)g,
                                   (__attribute__((address_space(3))) unsigned int*)l, 16, 0, 0);
}

// ---------------- weight prep: fp32 -> bf16, transposed to [N][K] ----------------
__global__ __launch_bounds__(256) void prep_qkv(const float* __restrict__ Wq,
                                                const float* __restrict__ Wk,
                                                const float* __restrict__ Wv,
                                                unsigned short* __restrict__ dst) {
  int tid = blockIdx.x * 256 + threadIdx.x;           // 2304*768 total, exact grid
  int n = tid / DM, k = tid - n * DM;
  int seg = n / DM;                                    // 0..2
  int within = n - seg * DM;
  int h = within >> 6, e = within & 63;
  const float* W = (seg == 0) ? Wq : (seg == 1) ? Wk : Wv;
  dst[tid] = f2bf(W[((size_t)h * DM + k) * HD + e]);
}

__global__ __launch_bounds__(256) void prep_t(const float* __restrict__ src,
                                              unsigned short* __restrict__ dst,
                                              int N, int K) {
  int tid = blockIdx.x * 256 + threadIdx.x;
  if (tid >= N * K) return;
  int n = tid / K, k = tid - n * K;
  dst[tid] = f2bf(src[(size_t)k * N + n]);
}

// ---------------- layernorm: fp32 [rows,768] -> bf16 [rows,768] ----------------
__global__ __launch_bounds__(256) void ln_bf16(const float* __restrict__ X,
                                               const float* __restrict__ g,
                                               const float* __restrict__ b,
                                               unsigned short* __restrict__ out) {
  int row  = blockIdx.x * 4 + (threadIdx.x >> 6);
  int lane = threadIdx.x & 63;
  const float* x = X + (size_t)row * DM;
  float4 v[3];
  float s = 0.f, s2 = 0.f;
#pragma unroll
  for (int i = 0; i < 3; i++) {
    v[i] = *(const float4*)(x + i * 256 + lane * 4);
    s  += v[i].x + v[i].y + v[i].z + v[i].w;
    s2 += v[i].x * v[i].x + v[i].y * v[i].y + v[i].z * v[i].z + v[i].w * v[i].w;
  }
#pragma unroll
  for (int o = 1; o < 64; o <<= 1) { s += __shfl_xor(s, o); s2 += __shfl_xor(s2, o); }
  float mu  = s * (1.f / DM);
  float var = s2 * (1.f / DM) - mu * mu;
  float inv = rsqrtf(var + 1e-6f);
#pragma unroll
  for (int i = 0; i < 3; i++) {
    int c = i * 256 + lane * 4;
    float4 gg = *(const float4*)(g + c);
    float4 bb = *(const float4*)(b + c);
    ushort4 o4;
    o4.x = f2bf((v[i].x - mu) * inv * gg.x + bb.x);
    o4.y = f2bf((v[i].y - mu) * inv * gg.y + bb.y);
    o4.z = f2bf((v[i].z - mu) * inv * gg.z + bb.z);
    o4.w = f2bf((v[i].w - mu) * inv * gg.w + bb.w);
    *(ushort4*)(out + (size_t)row * DM + c) = o4;
  }
}

// ---------------- tiled bf16 MFMA GEMM: C = A[M,K] * Bt[N,K]^T ----------------
// 128x128 tile, BK=32, 256 threads. Staging via global_load_lds width=16 (m97 lever).
template <int EPI>
__global__ __launch_bounds__(256) void gemm_bt(
    const unsigned short* __restrict__ A, const unsigned short* __restrict__ Bt,
    int M, int N, int K,
    const float* __restrict__ bias0, const float* __restrict__ bias1,
    const float* __restrict__ bias2, const float* __restrict__ xres,
    float* __restrict__ outf,
    unsigned short* __restrict__ ob0, unsigned short* __restrict__ ob1,
    unsigned short* __restrict__ ob2) {
  __shared__ __align__(16) unsigned short sA[128 * 32];
  __shared__ __align__(16) unsigned short sB[128 * 32];
  const int tid  = threadIdx.x;
  const int wave = tid >> 6, lane = tid & 63;
  const int l15 = lane & 15, quad = lane >> 4;
  const int m0 = blockIdx.y * 128, n0 = blockIdx.x * 128;
  const int wm = (wave >> 1) * 64, wn = (wave & 1) * 64;

  f32x4 acc[4][4] = {};
  const int nkt = K >> 5;
  for (int kt = 0; kt < nkt; ++kt) {
#pragma unroll
    for (int i = 0; i < 2; i++) {
      int c = tid + i * 256;
      int row = c >> 2, kc = (c & 3) << 3;
      int ra = m0 + row; if (ra >= M) ra = M - 1;           // clamp tail rows
      gload_lds16(A  + (size_t)ra * K         + (kt << 5) + kc, sA + row * 32 + kc);
      gload_lds16(Bt + (size_t)(n0 + row) * K + (kt << 5) + kc, sB + row * 32 + kc);
    }
    __syncthreads();
    bf16x8 aF[4], bF[4];
#pragma unroll
    for (int mi = 0; mi < 4; mi++) aF[mi] = *(const bf16x8*)(sA + (wm + mi * 16 + l15) * 32 + quad * 8);
#pragma unroll
    for (int ni = 0; ni < 4; ni++) bF[ni] = *(const bf16x8*)(sB + (wn + ni * 16 + l15) * 32 + quad * 8);
#pragma unroll
    for (int mi = 0; mi < 4; mi++)
#pragma unroll
      for (int ni = 0; ni < 4; ni++) acc[mi][ni] = mfma16(aF[mi], bF[ni], acc[mi][ni]);
    __syncthreads();
  }

#pragma unroll
  for (int mi = 0; mi < 4; mi++) {
#pragma unroll
    for (int r = 0; r < 4; r++) {
      int mg = m0 + wm + mi * 16 + quad * 4 + r;
      if (mg >= M) continue;
      if constexpr (EPI == 0) {
        int bb = mg / SEQ, ss = mg - bb * SEQ;
        int seg = n0 / DM;
        int within0 = n0 - seg * DM + wn;
#pragma unroll
        for (int ni = 0; ni < 4; ni++) {
          int wcol = within0 + ni * 16 + l15;
          int h = wcol >> 6, e = wcol & 63;
          float val = acc[mi][ni][r];
          if (seg == 0) {
            float qv = (val + bias0[wcol]) * 0.125f;   // fold 1/sqrt(64)
            ob0[((size_t)(bb * NH + h) * SEQ + ss) * HD + e] = f2bf(qv);
          } else if (seg == 1) {
            float kv = val + bias1[wcol];
            ob1[((size_t)(bb * NH + h) * SEQ + ss) * HD + e] = f2bf(kv);
          } else {
            float vv = val + bias2[wcol];
            ob2[((size_t)(bb * NH + h) * HD + e) * VTS + ss] = f2bf(vv);  // V transposed
          }
        }
      } else if constexpr (EPI == 1) {
        size_t base = (size_t)mg * DM;
#pragma unroll
        for (int ni = 0; ni < 4; ni++) {
          int col = n0 + wn + ni * 16 + l15;
          outf[base + col] = xres[base + col] + acc[mi][ni][r] + bias0[col];
        }
      } else if constexpr (EPI == 2) {
        size_t base = (size_t)mg * FFD;
#pragma unroll
        for (int ni = 0; ni < 4; ni++) {
          int col = n0 + wn + ni * 16 + l15;
          float xv = acc[mi][ni][r] + bias0[col];
          float u  = 0.7978845608028654f * (xv + 0.044715f * xv * xv * xv);
          float uc = fminf(fmaxf(u, -15.f), 15.f);
          float t  = __expf(2.f * uc);
          float gel = 0.5f * xv * (1.f + (t - 1.f) / (t + 1.f));
          ob0[base + col] = f2bf(gel);
        }
      } else {  // EPI == 3
        size_t base = (size_t)mg * DM;
#pragma unroll
        for (int ni = 0; ni < 4; ni++) {
          int col = n0 + wn + ni * 16 + l15;
          outf[base + col] += acc[mi][ni][r] + bias0[col];
        }
      }
    }
  }
}

// ---------------- flash attention: 256 thr, 64 q-rows/block, 64-t tiles ----------------
// K-tile [t][d] and V^T-tile [e][t] staged in LDS, shared by 4 waves (wave = 16 q-rows).
// Online softmax (running m,l), P transposed through per-wave LDS. Q pre-scaled by 1/8.
__global__ __launch_bounds__(256) void attn_fused(
    const unsigned short* __restrict__ Q, const unsigned short* __restrict__ Kb,
    const unsigned short* __restrict__ Vt, unsigned short* __restrict__ Cc) {
  __shared__ __align__(16) unsigned short sK[64 * 72];     // +8 pad breaks 128B-stride conflicts
  __shared__ __align__(16) unsigned short sV[64 * 72];
  __shared__ __align__(16) unsigned short sP[4][16 * 72];
  const int tid  = threadIdx.x;
  const int wave = tid >> 6, lane = tid & 63;
  const int quad = lane >> 4, l15 = lane & 15;
  const int bh = blockIdx.y;
  const int q0 = blockIdx.x * 64;

  int qr = q0 + wave * 16 + l15; if (qr > SEQ - 1) qr = SEQ - 1;   // clamp tail q rows
  const unsigned short* qrow = Q + ((size_t)bh * SEQ + qr) * HD;
  bf16x8 aQ0 = *(const bf16x8*)(qrow + quad * 8);
  bf16x8 aQ1 = *(const bf16x8*)(qrow + 32 + quad * 8);

  float m[4], l[4];
  f32x4 accO[4] = {};
#pragma unroll
  for (int r = 0; r < 4; r++) { m[r] = -3e38f; l[r] = 0.f; }

  for (int t0 = 0; t0 < SEQ; t0 += 64) {
    // stage K [64 t][64 d] and V^T [64 e][64 t] (coalesced 16B/lane)
#pragma unroll
    for (int i = 0; i < 2; i++) {
      int c = tid + i * 256;                 // 0..511
      int row = c >> 3, col = (c & 7) << 3;
      int tk = t0 + row; if (tk > SEQ - 1) tk = SEQ - 1;
      bf16x8 vk = *(const bf16x8*)(Kb + ((size_t)bh * SEQ + tk) * HD + col);
      bf16x8 vv = *(const bf16x8*)(Vt + ((size_t)bh * HD + row) * VTS + t0 + col);
      *(bf16x8*)(sK + row * 72 + col) = vk;
      *(bf16x8*)(sV + row * 72 + col) = vv;
    }
    __syncthreads();

    // QK^T: s[16 q][64 t] per wave
    f32x4 s4[4];
#pragma unroll
    for (int ni = 0; ni < 4; ni++) {
      bf16x8 b0 = *(const bf16x8*)(sK + (ni * 16 + l15) * 72 + quad * 8);
      bf16x8 b1 = *(const bf16x8*)(sK + (ni * 16 + l15) * 72 + 32 + quad * 8);
      f32x4 a = {0.f, 0.f, 0.f, 0.f};
      a = mfma16(aQ0, b0, a);
      a = mfma16(aQ1, b1, a);
      s4[ni] = a;
    }
    // mask invalid t columns
#pragma unroll
    for (int ni = 0; ni < 4; ni++) {
      if (t0 + ni * 16 + l15 >= SEQ) {
#pragma unroll
        for (int r = 0; r < 4; r++) s4[ni][r] = -3e38f;
      }
    }
    // online softmax update
    float mn[4], alpha[4], ts[4];
#pragma unroll
    for (int r = 0; r < 4; r++) {
      float tm = fmaxf(fmaxf(s4[0][r], s4[1][r]), fmaxf(s4[2][r], s4[3][r]));
#pragma unroll
      for (int o = 1; o < 16; o <<= 1) tm = fmaxf(tm, __shfl_xor(tm, o));
      mn[r] = fmaxf(m[r], tm);
      alpha[r] = __expf(m[r] - mn[r]);
      m[r] = mn[r];
      ts[r] = 0.f;
    }
#pragma unroll
    for (int ni = 0; ni < 4; ni++) {
#pragma unroll
      for (int r = 0; r < 4; r++) {
        float p = __expf(s4[ni][r] - mn[r]);
        ts[r] += p;
        sP[wave][(quad * 4 + r) * 72 + ni * 16 + l15] = f2bf(p);
      }
    }
#pragma unroll
    for (int r = 0; r < 4; r++) {
#pragma unroll
      for (int o = 1; o < 16; o <<= 1) ts[r] += __shfl_xor(ts[r], o);
      l[r] = l[r] * alpha[r] + ts[r];
#pragma unroll
      for (int ni = 0; ni < 4; ni++) accO[ni][r] *= alpha[r];
    }
    // PV: P [16 q][64 t] x V [64 t][64 e]  (P via per-wave LDS transpose, wave-ordered DS)
    bf16x8 aP0 = *(const bf16x8*)(sP[wave] + l15 * 72 + quad * 8);
    bf16x8 aP1 = *(const bf16x8*)(sP[wave] + l15 * 72 + 32 + quad * 8);
#pragma unroll
    for (int ni = 0; ni < 4; ni++) {
      bf16x8 v0 = *(const bf16x8*)(sV + (ni * 16 + l15) * 72 + quad * 8);
      bf16x8 v1 = *(const bf16x8*)(sV + (ni * 16 + l15) * 72 + 32 + quad * 8);
      accO[ni] = mfma16(aP0, v0, accO[ni]);
      accO[ni] = mfma16(aP1, v1, accO[ni]);
    }
    __syncthreads();
  }

  int bb = bh / NH, h = bh - bb * NH;
#pragma unroll
  for (int r = 0; r < 4; r++) {
    int ss = q0 + wave * 16 + quad * 4 + r;
    if (ss < SEQ) {
      float inv = 1.f / l[r];
      size_t base = ((size_t)bb * SEQ + ss) * DM + h * HD;
#pragma unroll
      for (int ni = 0; ni < 4; ni++)
        Cc[base + ni * 16 + l15] = f2bf(accO[ni][r] * inv);
    }
  }
}

// ---------------- host ----------------
extern "C" void kernel_launch(void* const* d_in, const int* in_sizes, int n_in,
                              void* d_out, int out_size, void* d_ws, size_t ws_size,
                              hipStream_t stream) {
  (void)in_sizes; (void)n_in; (void)out_size; (void)ws_size;
  const float* x     = (const float*)d_in[0];
  const float* ln1_g = (const float*)d_in[1];
  const float* ln1_b = (const float*)d_in[2];
  const float* Wq    = (const float*)d_in[3];
  const float* bq    = (const float*)d_in[4];
  const float* Wk    = (const float*)d_in[5];
  const float* bk    = (const float*)d_in[6];
  const float* Wv    = (const float*)d_in[7];
  const float* bv    = (const float*)d_in[8];
  const float* Wo    = (const float*)d_in[9];
  const float* bo    = (const float*)d_in[10];
  const float* ln2_g = (const float*)d_in[11];
  const float* ln2_b = (const float*)d_in[12];
  const float* W1    = (const float*)d_in[13];
  const float* b1    = (const float*)d_in[14];
  const float* W2    = (const float*)d_in[15];
  const float* b2    = (const float*)d_in[16];
  float* out = (float*)d_out;

  char* ws = (char*)d_ws;
  size_t off = 0;
  auto alloc = [&](size_t bytes) -> unsigned short* {
    unsigned short* p = (unsigned short*)(ws + off);
    off += (bytes + 255) & ~(size_t)255;
    return p;
  };
  unsigned short* h_bf  = alloc((size_t)ROWS * DM * 2);
  unsigned short* q_bf  = alloc((size_t)BHN * SEQ * HD * 2);
  unsigned short* k_bf  = alloc((size_t)BHN * SEQ * HD * 2);
  unsigned short* vt_bf = alloc((size_t)BHN * HD * VTS * 2);
  unsigned short* cc_bf = alloc((size_t)ROWS * DM * 2);
  // g_bf (226.9MB) aliases [q_bf ..) (236MB) — q/k/vt/cc dead by then
  unsigned short* g_bf = q_bf;
  unsigned short* wqkv_t = alloc((size_t)2304 * 768 * 2);
  unsigned short* w1_t   = alloc((size_t)3072 * 768 * 2);
  unsigned short* w2_t   = alloc((size_t)768 * 3072 * 2);
  unsigned short* wo_t   = alloc((size_t)768 * 768 * 2);

  prep_qkv<<<(2304 * 768) / 256, 256, 0, stream>>>(Wq, Wk, Wv, wqkv_t);
  prep_t<<<(3072 * 768) / 256, 256, 0, stream>>>(W1, w1_t, 3072, 768);
  prep_t<<<(768 * 3072) / 256, 256, 0, stream>>>(W2, w2_t, 768, 3072);
  prep_t<<<(768 * 768) / 256, 256, 0, stream>>>(Wo, wo_t, 768, 768);

  ln_bf16<<<ROWS / 4, 256, 0, stream>>>(x, ln1_g, ln1_b, h_bf);
  gemm_bt<0><<<dim3(2304 / 128, (ROWS + 127) / 128), 256, 0, stream>>>(
      h_bf, wqkv_t, ROWS, 2304, 768, bq, bk, bv, nullptr, nullptr, q_bf, k_bf, vt_bf);
  attn_fused<<<dim3((SEQ + 63) / 64, BHN), 256, 0, stream>>>(q_bf, k_bf, vt_bf, cc_bf);
  gemm_bt<1><<<dim3(768 / 128, (ROWS + 127) / 128), 256, 0, stream>>>(
      cc_bf, wo_t, ROWS, 768, 768, bo, nullptr, nullptr, x, out, nullptr, nullptr, nullptr);
  ln_bf16<<<ROWS / 4, 256, 0, stream>>>(out, ln2_g, ln2_b, h_bf);
  gemm_bt<2><<<dim3(3072 / 128, (ROWS + 127) / 128), 256, 0, stream>>>(
      h_bf, w1_t, ROWS, 3072, 768, b1, nullptr, nullptr, nullptr, nullptr, g_bf, nullptr, nullptr);
  gemm_bt<3><<<dim3(768 / 128, (ROWS + 127) / 128), 256, 0, stream>>>(
      g_bf, w2_t, ROWS, 768, 3072, b2, nullptr, nullptr, nullptr, out, nullptr, nullptr, nullptr);
}

// Round 4
// 1474.982 us; speedup vs baseline: 1.3153x; 1.0839x over previous
//
#include <hip/hip_runtime.h>
#include <stdint.h>

// ---------------- problem constants ----------------
constexpr int BZ   = 64;          // batch
constexpr int SEQ  = 577;         // sequence length
constexpr int DM   = 768;         // model dim
constexpr int NH   = 12;          // heads
constexpr int HD   = 64;          // head dim
constexpr int FFD  = 3072;        // mlp hidden
constexpr int ROWS = BZ * SEQ;    // 36928 token rows
constexpr int BHN  = BZ * NH;     // 768 (b,h) pairs
constexpr int VTS  = 640;         // padded t-stride for V^T

typedef __attribute__((ext_vector_type(8))) short bf16x8;  // 8 bf16 = 4 VGPRs
typedef __attribute__((ext_vector_type(4))) float f32x4;   // MFMA C/D frag

static __device__ __forceinline__ unsigned short f2bf(float f) {
  union { float f; uint32_t u; } v; v.f = f;
  uint32_t r = (v.u + 0x7FFFu + ((v.u >> 16) & 1u)) >> 16;  // RNE
  return (unsigned short)r;
}

static __device__ __forceinline__ f32x4 mfma16(bf16x8 a, bf16x8 b, f32x4 c) {
  return __builtin_amdgcn_mfma_f32_16x16x32_bf16(a, b, c, 0, 0, 0);
}

// async global->LDS, 16B per lane; LDS dest = wave-uniform base + lane*16.
static __device__ __forceinline__ void gload_lds16(const unsigned short* g, unsigned short* l) {
  __builtin_amdgcn_global_load_lds((const __attribute__((address_space(1))) unsigned int*)g,
                                   (__attribute__((address_space(3))) unsigned int*)l, 16, 0, 0);
}

// ---------------- weight prep: fp32 -> bf16, transposed to [N][K] ----------------
__global__ __launch_bounds__(256) void prep_qkv(const float* __restrict__ Wq,
                                                const float* __restrict__ Wk,
                                                const float* __restrict__ Wv,
                                                unsigned short* __restrict__ dst) {
  int tid = blockIdx.x * 256 + threadIdx.x;           // 2304*768 total, exact grid
  int n = tid / DM, k = tid - n * DM;
  int seg = n / DM;                                    // 0..2
  int within = n - seg * DM;
  int h = within >> 6, e = within & 63;
  const float* W = (seg == 0) ? Wq : (seg == 1) ? Wk : Wv;
  dst[tid] = f2bf(W[((size_t)h * DM + k) * HD + e]);
}

__global__ __launch_bounds__(256) void prep_t(const float* __restrict__ src,
                                              unsigned short* __restrict__ dst,
                                              int N, int K) {
  int tid = blockIdx.x * 256 + threadIdx.x;
  if (tid >= N * K) return;
  int n = tid / K, k = tid - n * K;
  dst[tid] = f2bf(src[(size_t)k * N + n]);
}

// ---------------- layernorm: fp32 [rows,768] -> bf16 [rows,768] ----------------
__global__ __launch_bounds__(256) void ln_bf16(const float* __restrict__ X,
                                               const float* __restrict__ g,
                                               const float* __restrict__ b,
                                               unsigned short* __restrict__ out) {
  int row  = blockIdx.x * 4 + (threadIdx.x >> 6);
  int lane = threadIdx.x & 63;
  const float* x = X + (size_t)row * DM;
  float4 v[3];
  float s = 0.f, s2 = 0.f;
#pragma unroll
  for (int i = 0; i < 3; i++) {
    v[i] = *(const float4*)(x + i * 256 + lane * 4);
    s  += v[i].x + v[i].y + v[i].z + v[i].w;
    s2 += v[i].x * v[i].x + v[i].y * v[i].y + v[i].z * v[i].z + v[i].w * v[i].w;
  }
#pragma unroll
  for (int o = 1; o < 64; o <<= 1) { s += __shfl_xor(s, o); s2 += __shfl_xor(s2, o); }
  float mu  = s * (1.f / DM);
  float var = s2 * (1.f / DM) - mu * mu;
  float inv = rsqrtf(var + 1e-6f);
#pragma unroll
  for (int i = 0; i < 3; i++) {
    int c = i * 256 + lane * 4;
    float4 gg = *(const float4*)(g + c);
    float4 bb = *(const float4*)(b + c);
    ushort4 o4;
    o4.x = f2bf((v[i].x - mu) * inv * gg.x + bb.x);
    o4.y = f2bf((v[i].y - mu) * inv * gg.y + bb.y);
    o4.z = f2bf((v[i].z - mu) * inv * gg.z + bb.z);
    o4.w = f2bf((v[i].w - mu) * inv * gg.w + bb.w);
    *(ushort4*)(out + (size_t)row * DM + c) = o4;
  }
}

// ---------------- tiled bf16 MFMA GEMM: C = A[M,K] * Bt[N,K]^T ----------------
// 128x128 tile, BK=64 (halves barrier drains), 256 threads.
// XOR chunk swizzle: LDS slot (row, col) holds global k-chunk col^(row&7) —
// keeps global_load_lds's linear LDS dest, makes ds_read_b128 phases 2-way (free).
// 1D grid, XCD-chunked remap: each XCD gets a contiguous (m,n)-range so n-blocks
// sharing an A-stripe hit the same per-XCD L2.
template <int EPI>
__global__ __launch_bounds__(256) void gemm_bt(
    const unsigned short* __restrict__ A, const unsigned short* __restrict__ Bt,
    int M, int N, int K, int nbn,
    const float* __restrict__ bias0, const float* __restrict__ bias1,
    const float* __restrict__ bias2, const float* __restrict__ xres,
    float* __restrict__ outf,
    unsigned short* __restrict__ ob0, unsigned short* __restrict__ ob1,
    unsigned short* __restrict__ ob2) {
  __shared__ __align__(16) unsigned short sA[128 * 64];
  __shared__ __align__(16) unsigned short sB[128 * 64];
  const int tid  = threadIdx.x;
  const int wave = tid >> 6;
  const int lane = tid & 63;
  const int l15 = lane & 15, quad = lane >> 4;

  // bijective XCD-chunk remap: blocks with L%8==x (same XCD) get consecutive g
  const int nb = gridDim.x;
  const int L = blockIdx.x;
  const int per = nb >> 3, rem = nb & 7;
  const int x8 = L & 7, i8 = L >> 3;
  const int g = x8 * per + (x8 < rem ? x8 : rem) + i8;
  const int mt = g / nbn, nt = g - mt * nbn;
  const int m0 = mt * 128, n0 = nt * 128;
  const int wm = (wave >> 1) * 64, wn = (wave & 1) * 64;

  f32x4 acc[4][4] = {};
  const int nkt = K >> 6;
  for (int kt = 0; kt < nkt; ++kt) {
    // stage 16KB A + 16KB B; global chunk XOR-permuted per row, LDS stays linear
#pragma unroll
    for (int j = 0; j < 4; j++) {
      int c = tid + j * 256;                 // 0..1023
      int row = c >> 3, col = c & 7;
      int kc = col ^ (row & 7);
      int ra = m0 + row; if (ra >= M) ra = M - 1;           // clamp tail rows
      gload_lds16(A  + (size_t)ra * K         + (kt << 6) + kc * 8, sA + c * 8);
      gload_lds16(Bt + (size_t)(n0 + row) * K + (kt << 6) + kc * 8, sB + c * 8);
    }
    __syncthreads();
#pragma unroll
    for (int h = 0; h < 2; h++) {
      bf16x8 aF[4], bF[4];
      const int swz = ((h << 2) | quad) ^ (l15 & 7);   // row ≡ l15 mod 8 for all frags
#pragma unroll
      for (int mi = 0; mi < 4; mi++) aF[mi] = *(const bf16x8*)(sA + (wm + mi * 16 + l15) * 64 + swz * 8);
#pragma unroll
      for (int ni = 0; ni < 4; ni++) bF[ni] = *(const bf16x8*)(sB + (wn + ni * 16 + l15) * 64 + swz * 8);
#pragma unroll
      for (int mi = 0; mi < 4; mi++)
#pragma unroll
        for (int ni = 0; ni < 4; ni++) acc[mi][ni] = mfma16(aF[mi], bF[ni], acc[mi][ni]);
    }
    __syncthreads();
  }

#pragma unroll
  for (int mi = 0; mi < 4; mi++) {
#pragma unroll
    for (int r = 0; r < 4; r++) {
      int mg = m0 + wm + mi * 16 + quad * 4 + r;
      if (mg >= M) continue;
      if constexpr (EPI == 0) {
        int bb = mg / SEQ, ss = mg - bb * SEQ;
        int seg = n0 / DM;
        int within0 = n0 - seg * DM + wn;
#pragma unroll
        for (int ni = 0; ni < 4; ni++) {
          int wcol = within0 + ni * 16 + l15;
          int h = wcol >> 6, e = wcol & 63;
          float val = acc[mi][ni][r];
          if (seg == 0) {
            float qv = (val + bias0[wcol]) * 0.125f;   // fold 1/sqrt(64)
            ob0[((size_t)(bb * NH + h) * SEQ + ss) * HD + e] = f2bf(qv);
          } else if (seg == 1) {
            float kv = val + bias1[wcol];
            ob1[((size_t)(bb * NH + h) * SEQ + ss) * HD + e] = f2bf(kv);
          } else {
            float vv = val + bias2[wcol];
            ob2[((size_t)(bb * NH + h) * HD + e) * VTS + ss] = f2bf(vv);  // V transposed
          }
        }
      } else if constexpr (EPI == 1) {
        size_t base = (size_t)mg * DM;
#pragma unroll
        for (int ni = 0; ni < 4; ni++) {
          int col = n0 + wn + ni * 16 + l15;
          outf[base + col] = xres[base + col] + acc[mi][ni][r] + bias0[col];
        }
      } else if constexpr (EPI == 2) {
        size_t base = (size_t)mg * FFD;
#pragma unroll
        for (int ni = 0; ni < 4; ni++) {
          int col = n0 + wn + ni * 16 + l15;
          float xv = acc[mi][ni][r] + bias0[col];
          float u  = 0.7978845608028654f * (xv + 0.044715f * xv * xv * xv);
          float uc = fminf(fmaxf(u, -15.f), 15.f);
          float t  = __expf(2.f * uc);
          float gel = 0.5f * xv * (1.f + (t - 1.f) / (t + 1.f));
          ob0[base + col] = f2bf(gel);
        }
      } else {  // EPI == 3
        size_t base = (size_t)mg * DM;
#pragma unroll
        for (int ni = 0; ni < 4; ni++) {
          int col = n0 + wn + ni * 16 + l15;
          outf[base + col] += acc[mi][ni][r] + bias0[col];
        }
      }
    }
  }
}

// ---------------- flash attention: 256 thr, 64 q-rows/block, 64-t tiles ----------------
__global__ __launch_bounds__(256) void attn_fused(
    const unsigned short* __restrict__ Q, const unsigned short* __restrict__ Kb,
    const unsigned short* __restrict__ Vt, unsigned short* __restrict__ Cc) {
  __shared__ __align__(16) unsigned short sK[64 * 72];     // +8 pad breaks 128B-stride conflicts
  __shared__ __align__(16) unsigned short sV[64 * 72];
  __shared__ __align__(16) unsigned short sP[4][16 * 72];
  const int tid  = threadIdx.x;
  const int wave = tid >> 6, lane = tid & 63;
  const int quad = lane >> 4, l15 = lane & 15;
  const int bh = blockIdx.y;
  const int q0 = blockIdx.x * 64;

  int qr = q0 + wave * 16 + l15; if (qr > SEQ - 1) qr = SEQ - 1;   // clamp tail q rows
  const unsigned short* qrow = Q + ((size_t)bh * SEQ + qr) * HD;
  bf16x8 aQ0 = *(const bf16x8*)(qrow + quad * 8);
  bf16x8 aQ1 = *(const bf16x8*)(qrow + 32 + quad * 8);

  float m[4], l[4];
  f32x4 accO[4] = {};
#pragma unroll
  for (int r = 0; r < 4; r++) { m[r] = -3e38f; l[r] = 0.f; }

  for (int t0 = 0; t0 < SEQ; t0 += 64) {
#pragma unroll
    for (int i = 0; i < 2; i++) {
      int c = tid + i * 256;                 // 0..511
      int row = c >> 3, col = (c & 7) << 3;
      int tk = t0 + row; if (tk > SEQ - 1) tk = SEQ - 1;
      bf16x8 vk = *(const bf16x8*)(Kb + ((size_t)bh * SEQ + tk) * HD + col);
      bf16x8 vv = *(const bf16x8*)(Vt + ((size_t)bh * HD + row) * VTS + t0 + col);
      *(bf16x8*)(sK + row * 72 + col) = vk;
      *(bf16x8*)(sV + row * 72 + col) = vv;
    }
    __syncthreads();

    f32x4 s4[4];
#pragma unroll
    for (int ni = 0; ni < 4; ni++) {
      bf16x8 b0 = *(const bf16x8*)(sK + (ni * 16 + l15) * 72 + quad * 8);
      bf16x8 b1 = *(const bf16x8*)(sK + (ni * 16 + l15) * 72 + 32 + quad * 8);
      f32x4 a = {0.f, 0.f, 0.f, 0.f};
      a = mfma16(aQ0, b0, a);
      a = mfma16(aQ1, b1, a);
      s4[ni] = a;
    }
#pragma unroll
    for (int ni = 0; ni < 4; ni++) {
      if (t0 + ni * 16 + l15 >= SEQ) {
#pragma unroll
        for (int r = 0; r < 4; r++) s4[ni][r] = -3e38f;
      }
    }
    float mn[4], alpha[4], ts[4];
#pragma unroll
    for (int r = 0; r < 4; r++) {
      float tm = fmaxf(fmaxf(s4[0][r], s4[1][r]), fmaxf(s4[2][r], s4[3][r]));
#pragma unroll
      for (int o = 1; o < 16; o <<= 1) tm = fmaxf(tm, __shfl_xor(tm, o));
      mn[r] = fmaxf(m[r], tm);
      alpha[r] = __expf(m[r] - mn[r]);
      m[r] = mn[r];
      ts[r] = 0.f;
    }
#pragma unroll
    for (int ni = 0; ni < 4; ni++) {
#pragma unroll
      for (int r = 0; r < 4; r++) {
        float p = __expf(s4[ni][r] - mn[r]);
        ts[r] += p;
        sP[wave][(quad * 4 + r) * 72 + ni * 16 + l15] = f2bf(p);
      }
    }
#pragma unroll
    for (int r = 0; r < 4; r++) {
#pragma unroll
      for (int o = 1; o < 16; o <<= 1) ts[r] += __shfl_xor(ts[r], o);
      l[r] = l[r] * alpha[r] + ts[r];
#pragma unroll
      for (int ni = 0; ni < 4; ni++) accO[ni][r] *= alpha[r];
    }
    bf16x8 aP0 = *(const bf16x8*)(sP[wave] + l15 * 72 + quad * 8);
    bf16x8 aP1 = *(const bf16x8*)(sP[wave] + l15 * 72 + 32 + quad * 8);
#pragma unroll
    for (int ni = 0; ni < 4; ni++) {
      bf16x8 v0 = *(const bf16x8*)(sV + (ni * 16 + l15) * 72 + quad * 8);
      bf16x8 v1 = *(const bf16x8*)(sV + (ni * 16 + l15) * 72 + 32 + quad * 8);
      accO[ni] = mfma16(aP0, v0, accO[ni]);
      accO[ni] = mfma16(aP1, v1, accO[ni]);
    }
    __syncthreads();
  }

  int bb = bh / NH, h = bh - bb * NH;
#pragma unroll
  for (int r = 0; r < 4; r++) {
    int ss = q0 + wave * 16 + quad * 4 + r;
    if (ss < SEQ) {
      float inv = 1.f / l[r];
      size_t base = ((size_t)bb * SEQ + ss) * DM + h * HD;
#pragma unroll
      for (int ni = 0; ni < 4; ni++)
        Cc[base + ni * 16 + l15] = f2bf(accO[ni][r] * inv);
    }
  }
}

// ---------------- host ----------------
extern "C" void kernel_launch(void* const* d_in, const int* in_sizes, int n_in,
                              void* d_out, int out_size, void* d_ws, size_t ws_size,
                              hipStream_t stream) {
  (void)in_sizes; (void)n_in; (void)out_size; (void)ws_size;
  const float* x     = (const float*)d_in[0];
  const float* ln1_g = (const float*)d_in[1];
  const float* ln1_b = (const float*)d_in[2];
  const float* Wq    = (const float*)d_in[3];
  const float* bq    = (const float*)d_in[4];
  const float* Wk    = (const float*)d_in[5];
  const float* bk    = (const float*)d_in[6];
  const float* Wv    = (const float*)d_in[7];
  const float* bv    = (const float*)d_in[8];
  const float* Wo    = (const float*)d_in[9];
  const float* bo    = (const float*)d_in[10];
  const float* ln2_g = (const float*)d_in[11];
  const float* ln2_b = (const float*)d_in[12];
  const float* W1    = (const float*)d_in[13];
  const float* b1    = (const float*)d_in[14];
  const float* W2    = (const float*)d_in[15];
  const float* b2    = (const float*)d_in[16];
  float* out = (float*)d_out;

  char* ws = (char*)d_ws;
  size_t off = 0;
  auto alloc = [&](size_t bytes) -> unsigned short* {
    unsigned short* p = (unsigned short*)(ws + off);
    off += (bytes + 255) & ~(size_t)255;
    return p;
  };
  unsigned short* h_bf  = alloc((size_t)ROWS * DM * 2);
  unsigned short* q_bf  = alloc((size_t)BHN * SEQ * HD * 2);
  unsigned short* k_bf  = alloc((size_t)BHN * SEQ * HD * 2);
  unsigned short* vt_bf = alloc((size_t)BHN * HD * VTS * 2);
  unsigned short* cc_bf = alloc((size_t)ROWS * DM * 2);
  // g_bf (226.9MB) aliases [q_bf ..) — q/k/vt/cc dead by then
  unsigned short* g_bf = q_bf;
  unsigned short* wqkv_t = alloc((size_t)2304 * 768 * 2);
  unsigned short* w1_t   = alloc((size_t)3072 * 768 * 2);
  unsigned short* w2_t   = alloc((size_t)768 * 3072 * 2);
  unsigned short* wo_t   = alloc((size_t)768 * 768 * 2);

  prep_qkv<<<(2304 * 768) / 256, 256, 0, stream>>>(Wq, Wk, Wv, wqkv_t);
  prep_t<<<(3072 * 768) / 256, 256, 0, stream>>>(W1, w1_t, 3072, 768);
  prep_t<<<(768 * 3072) / 256, 256, 0, stream>>>(W2, w2_t, 768, 3072);
  prep_t<<<(768 * 768) / 256, 256, 0, stream>>>(Wo, wo_t, 768, 768);

  const int MB = (ROWS + 127) / 128;   // 289 m-tiles

  ln_bf16<<<ROWS / 4, 256, 0, stream>>>(x, ln1_g, ln1_b, h_bf);
  gemm_bt<0><<<MB * 18, 256, 0, stream>>>(
      h_bf, wqkv_t, ROWS, 2304, 768, 18, bq, bk, bv, nullptr, nullptr, q_bf, k_bf, vt_bf);
  attn_fused<<<dim3((SEQ + 63) / 64, BHN), 256, 0, stream>>>(q_bf, k_bf, vt_bf, cc_bf);
  gemm_bt<1><<<MB * 6, 256, 0, stream>>>(
      cc_bf, wo_t, ROWS, 768, 768, 6, bo, nullptr, nullptr, x, out, nullptr, nullptr, nullptr);
  ln_bf16<<<ROWS / 4, 256, 0, stream>>>(out, ln2_g, ln2_b, h_bf);
  gemm_bt<2><<<MB * 24, 256, 0, stream>>>(
      h_bf, w1_t, ROWS, 3072, 768, 24, b1, nullptr, nullptr, nullptr, nullptr, g_bf, nullptr, nullptr);
  gemm_bt<3><<<MB * 6, 256, 0, stream>>>(
      g_bf, w2_t, ROWS, 768, 3072, 6, b2, nullptr, nullptr, nullptr, out, nullptr, nullptr, nullptr);
}